// Round 5
// baseline (343.585 us; speedup 1.0000x reference)
//
#include <hip/hip_runtime.h>
#include <math.h>

#define NWAVE   8
#define NORBIT  64
#define NATOMS  16384
#define NPAIRS  524288
#define HID     64
#define OC_LOOP 3
#define NSPEC   117
#define TBLN    (NSPEC * NSPEC)
#define NPADC   (NPAIRS + NATOMS * 8)   // 655360 max padded slots

// ---------- helpers ----------
__device__ __forceinline__ float wred_sum(float v) {
#pragma unroll
    for (int o = 1; o < 64; o <<= 1) v += __shfl_xor(v, o, 64);
    return v;
}

__device__ __forceinline__ float ln_silu(float h, float gg, float bb) {
    float m = wred_sum(h) * (1.f / 64.f);
    float c = h - m;
    float v = wred_sum(c * c) * (1.f / 64.f);
    float y = c * rsqrtf(v + 1e-5f) * gg + bb;
    return y / (1.f + expf(-y));
}

__device__ __forceinline__ float dot4(float4 a, float4 b) {
    return a.x * b.x + a.y * b.y + a.z * b.z + a.w * b.w;
}

// ---------- CSR build (padded to multiple of 8 per atom) ----------
__global__ void k_hist(const int* __restrict__ ai0, int* __restrict__ cnt) {
    int p = blockIdx.x * 256 + threadIdx.x;
    if (p < NPAIRS) atomicAdd(&cnt[ai0[p]], 1);
}

__global__ void k_scan(const int* __restrict__ cnt, int* __restrict__ offs,
                       int* __restrict__ cursor) {
    __shared__ int sums[1024];
    int t = threadIdx.x;
    int base = t * 16;
    int v[16];
    int s = 0;
#pragma unroll
    for (int u = 0; u < 16; u++) { v[u] = (cnt[base + u] + 7) & ~7; s += v[u]; }
    sums[t] = s;
    __syncthreads();
    for (int d = 1; d < 1024; d <<= 1) {
        int x = (t >= d) ? sums[t - d] : 0;
        __syncthreads();
        sums[t] += x;
        __syncthreads();
    }
    int run = (t == 0) ? 0 : sums[t - 1];
#pragma unroll
    for (int u = 0; u < 16; u++) {
        offs[base + u] = run;
        cursor[base + u] = run;
        run += v[u];
    }
    if (t == 1023) offs[NATOMS] = run;
}

__global__ void k_scatter(const int* __restrict__ ai0, int* __restrict__ cursor,
                          int* __restrict__ plist) {
    int p = blockIdx.x * 256 + threadIdx.x;
    if (p < NPAIRS) {
        int pos = atomicAdd(&cursor[ai0[p]], 1);
        plist[pos] = p;
    }
}

// ---------- weight transposes ----------
__global__ void k_prep(const float* __restrict__ embc_W2, const float* __restrict__ oc_W2,
                       const float* __restrict__ ccoeff,
                       float* __restrict__ embc_W2t, float* __restrict__ oc_W2t,
                       float* __restrict__ cct) {
    int idx = blockIdx.x * 256 + threadIdx.x;
    if (idx < 4096) {
        int o = idx >> 6, i = idx & 63;
        embc_W2t[o * 64 + i] = embc_W2[i * 64 + o];
    }
    int t = idx - 4096;
    if (t >= 0 && t < 1536) {
        int l = t >> 9, r = t & 511, o = r >> 6, i = r & 63;
        oc_W2t[l * 512 + o * 64 + i] = oc_W2[l * 512 + i * 8 + o];
    }
    t = idx - 5632;
    if (t >= 0 && t < 4096) {
        int lr = t >> 9, km = t & 511, k = km >> 6, m = km & 63;
        cct[(lr * 64 + m) * 8 + k] = ccoeff[(lr * 8 + k) * 64 + m];
    }
}

// ---------- embc MLP per atom ----------
__global__ void k_center(const int* __restrict__ spec,
                         const float* __restrict__ W1, const float* __restrict__ b1,
                         const float* __restrict__ g,  const float* __restrict__ be,
                         const float* __restrict__ W2t, const float* __restrict__ b2,
                         float* __restrict__ ccoef) {
    __shared__ float h_s[4][64];
    int lane = threadIdx.x & 63, slot = threadIdx.x >> 6;
    int atom = blockIdx.x * 4 + slot;
    int s = spec[atom] + 1;
    float h = W1[s * 64 + lane] + b1[lane];
    h = ln_silu(h, g[lane], be[lane]);
    h_s[slot][lane] = h;
    __syncthreads();
    float o = b2[lane];
    const float4* wp = (const float4*)(W2t + lane * 64);
    const float4* hp = (const float4*)h_s[slot];
#pragma unroll
    for (int t = 0; t < 16; t++) o += dot4(wp[t], hp[t]);
    ccoef[atom * 64 + lane] = o;
}

// ---------- embn MLP per unique species pair ----------
__global__ void k_table(const float* __restrict__ W1, const float* __restrict__ b1,
                        const float* __restrict__ g,  const float* __restrict__ be,
                        const float* __restrict__ W2, const float* __restrict__ b2,
                        float* __restrict__ table) {
    __shared__ float h_s[4][64];
    int lane = threadIdx.x & 63, slot = threadIdx.x >> 6;
    int key = blockIdx.x * 4 + slot;
    int kk = (key < TBLN) ? key : 0;
    int s0 = kk / NSPEC + 1, s1 = kk % NSPEC + 1;
    float h = W1[s0 * 64 + lane] + W1[s1 * 64 + lane] + b1[lane];
    h = ln_silu(h, g[lane], be[lane]);
    h_s[slot][lane] = h;
    __syncthreads();
    if (lane < 24 && key < TBLN) {
        float o = b2[lane];
#pragma unroll 8
        for (int i = 0; i < 64; i++) o += h_s[slot][i] * W2[i * 24 + lane];
        table[key * 24 + lane] = o;
    }
}

// ---------- per-pair: pair-major streams ----------
__global__ void k_pair2(const float* __restrict__ cart, const int* __restrict__ aidx,
                        const int* __restrict__ spec,  const float* __restrict__ table,
                        const int* __restrict__ plist, const int* __restrict__ total_p,
                        float* __restrict__ dist_out, float4* __restrict__ ang,
                        float4* __restrict__ rad2,    int* __restrict__ keyv,
                        int* __restrict__ neigh) {
    int pos = blockIdx.x * 256 + threadIdx.x;
    if (pos >= total_p[0]) return;
    int p = plist[pos];
    if (p < 0) {  // pad slot: zero contribution
        float4 z = make_float4(0.f, 0.f, 0.f, 0.f);
        ang[pos] = z;
        rad2[2 * pos] = z;
        rad2[2 * pos + 1] = z;
        keyv[pos] = 0;
        neigh[pos] = 0;
        return;
    }
    int i0 = aidx[p];
    int i1 = aidx[NPAIRS + p];
    float dv0 = cart[i0 * 3 + 0] - cart[i1 * 3 + 0];
    float dv1 = cart[i0 * 3 + 1] - cart[i1 * 3 + 1];
    float dv2 = cart[i0 * 3 + 2] - cart[i1 * 3 + 2];
    float d = sqrtf(dv0 * dv0 + dv1 * dv1 + dv2 * dv2);
    dist_out[(size_t)p * 3 + 0] = dv0;
    dist_out[(size_t)p * 3 + 1] = dv1;
    dist_out[(size_t)p * 3 + 2] = dv2;

    int key = spec[i0] * NSPEC + spec[i1];
    const float4* ne = (const float4*)(table + (size_t)key * 24);
    float4 al_a = ne[2], al_b = ne[3];
    float4 mu_a = ne[4], mu_b = ne[5];

    float cth = cosf(d * (float)(M_PI / 4.0));
    float t0 = 0.5f * cth + 0.5f;
    float fc = t0 * t0;
    ang[pos] = make_float4(fc, dv0 * fc, dv1 * fc, dv2 * fc);

    float4 r_a, r_b;
    float t;
    t = al_a.x * (d - mu_a.x); r_a.x = expf(-t * t);
    t = al_a.y * (d - mu_a.y); r_a.y = expf(-t * t);
    t = al_a.z * (d - mu_a.z); r_a.z = expf(-t * t);
    t = al_a.w * (d - mu_a.w); r_a.w = expf(-t * t);
    t = al_b.x * (d - mu_b.x); r_b.x = expf(-t * t);
    t = al_b.y * (d - mu_b.y); r_b.y = expf(-t * t);
    t = al_b.z * (d - mu_b.z); r_b.z = expf(-t * t);
    t = al_b.w * (d - mu_b.w); r_b.w = expf(-t * t);
    rad2[2 * pos] = r_a;
    rad2[2 * pos + 1] = r_b;
    keyv[pos] = key;
    neigh[pos] = i1;
}

// ---------- gather pass: one wave per atom, lane = position ----------
template <bool PASS0>
__global__ void k_co(const int* __restrict__ offs,
                     const float4* __restrict__ ang, const float4* __restrict__ rad2,
                     const int* __restrict__ keyv,  const float* __restrict__ table,
                     const int* __restrict__ neigh, const float* __restrict__ S_in,
                     const float* __restrict__ co0, float* __restrict__ co_out) {
    int lane = threadIdx.x & 63;
    int atom = (blockIdx.x * 256 + threadIdx.x) >> 6;
    int start = offs[atom], end = offs[atom + 1];
    float acc[32];
#pragma unroll
    for (int i = 0; i < 32; i++) acc[i] = 0.f;
    for (int p = start + lane; p < end; p += 64) {
        float4 a = ang[p];
        float4 r0 = rad2[2 * p], r1 = rad2[2 * p + 1];
        float4 w0, w1;
        if (PASS0) {
            int ky = keyv[p];
            const float4* tb = (const float4*)(table + (size_t)ky * 24);
            w0 = tb[0]; w1 = tb[1];
        } else {
            int n = neigh[p];
            const float4* sp = (const float4*)(S_in + (size_t)n * 8);
            w0 = sp[0]; w1 = sp[1];
        }
        float rw[8];
        rw[0] = r0.x * w0.x; rw[1] = r0.y * w0.y; rw[2] = r0.z * w0.z; rw[3] = r0.w * w0.w;
        rw[4] = r1.x * w1.x; rw[5] = r1.y * w1.y; rw[6] = r1.z * w1.z; rw[7] = r1.w * w1.w;
        float av[4] = {a.x, a.y, a.z, a.w};
#pragma unroll
        for (int j = 0; j < 4; j++)
#pragma unroll
            for (int k = 0; k < 8; k++)
                acc[j * 8 + k] += av[j] * rw[k];
    }
    // reduce-scatter: after 5 steps lane holds total for idx = lane&31
#pragma unroll
    for (int s = 0; s < 5; s++) {
        int o = 1 << s;
        bool b = (lane >> s) & 1;
#pragma unroll
        for (int i = 0; i < 16; i++) {
            if (i < (16 >> s)) {
                float keep = b ? acc[2 * i + 1] : acc[2 * i];
                float send = b ? acc[2 * i] : acc[2 * i + 1];
                acc[i] = keep + __shfl_xor(send, o, 64);
            }
        }
    }
    acc[0] += __shfl_xor(acc[0], 32, 64);
    if (lane < 32) {
        float v = acc[0];
        if (!PASS0) v += co0[(size_t)atom * 32 + lane];
        co_out[(size_t)atom * 32 + lane] = v;
    }
}

// ---------- contraction + oc MLP, weights LDS-staged, 64 atoms/block ----------
template <bool ACC>
__global__ void k_dmlp(const float* __restrict__ co, const float* __restrict__ ccoef,
                       const float* __restrict__ cct_l,
                       const float* __restrict__ W1, const float* __restrict__ b1,
                       const float* __restrict__ g,  const float* __restrict__ be,
                       const float* __restrict__ W2t, const float* __restrict__ b2,
                       const float* __restrict__ S_in, float* __restrict__ S_out) {
    __shared__ float w1_s[4096];
    __shared__ float cct_s[1024];
    __shared__ float w2_s[512];
    __shared__ float b1_s[64], g_s[64], be_s[64], b2_s[8];
    __shared__ float dens_s[4][64], h_s[4][64];
    int t = threadIdx.x;
    for (int i = t; i < 1024; i += 256) ((float4*)w1_s)[i] = ((const float4*)W1)[i];
    if (t < 256) ((float4*)cct_s)[t] = ((const float4*)cct_l)[t];
    if (t < 128) ((float4*)w2_s)[t] = ((const float4*)W2t)[t];
    if (t < 64) { b1_s[t] = b1[t]; g_s[t] = g[t]; be_s[t] = be[t]; }
    if (t >= 64 && t < 72) b2_s[t - 64] = b2[t - 64];
    __syncthreads();

    int lane = t & 63, slot = t >> 6;
    int abase = blockIdx.x * 64;
#pragma unroll 1
    for (int gi = 0; gi < 16; gi++) {
        int atom = abase + gi * 4 + slot;
        float cr[32];
        const float4* cp = (const float4*)(co + (size_t)atom * 32);
#pragma unroll
        for (int q = 0; q < 8; q++) {
            float4 v = cp[q];
            cr[q * 4 + 0] = v.x; cr[q * 4 + 1] = v.y; cr[q * 4 + 2] = v.z; cr[q * 4 + 3] = v.w;
        }
        const float4* c0 = (const float4*)(cct_s + lane * 8);
        const float4* c1 = (const float4*)(cct_s + 512 + lane * 8);
        float4 ca0 = c0[0], ca1 = c0[1];
        float4 cb0 = c1[0], cb1 = c1[1];
        float dens = ccoef[(size_t)atom * 64 + lane];
        {
            float s = cr[0] * ca0.x + cr[1] * ca0.y + cr[2] * ca0.z + cr[3] * ca0.w
                    + cr[4] * ca1.x + cr[5] * ca1.y + cr[6] * ca1.z + cr[7] * ca1.w;
            dens += s * s;
        }
#pragma unroll
        for (int jj = 1; jj < 4; jj++) {
            const float* cj = cr + jj * 8;
            float s = cj[0] * cb0.x + cj[1] * cb0.y + cj[2] * cb0.z + cj[3] * cb0.w
                    + cj[4] * cb1.x + cj[5] * cb1.y + cj[6] * cb1.z + cj[7] * cb1.w;
            dens += s * s;
        }
        dens_s[slot][lane] = dens;
        __syncthreads();

        float h = b1_s[lane];
#pragma unroll 16
        for (int i = 0; i < 64; i++) h += dens_s[slot][i] * w1_s[i * 64 + lane];
        h = ln_silu(h, g_s[lane], be_s[lane]);
        h_s[slot][lane] = h;
        __syncthreads();

        int o = lane >> 3, seg = lane & 7;
        const float4* w2p = (const float4*)(w2_s + o * 64 + seg * 8);
        const float4* hp  = (const float4*)(&h_s[slot][seg * 8]);
        float part = dot4(w2p[0], hp[0]) + dot4(w2p[1], hp[1]);
        part += __shfl_xor(part, 1, 64);
        part += __shfl_xor(part, 2, 64);
        part += __shfl_xor(part, 4, 64);
        if (seg == 0) {
            float val = part + b2_s[o];
            if (ACC) val += S_in[(size_t)atom * 8 + o];
            S_out[(size_t)atom * 8 + o] = val;
        }
        __syncthreads();
    }
}

// ---------- contraction + out MLP -> scalar, 64 atoms/block ----------
__global__ void k_dmlp_out(const float* __restrict__ co, const float* __restrict__ ccoef,
                           const float* __restrict__ cct_l, const int* __restrict__ spec,
                           const float* __restrict__ W1, const float* __restrict__ b1,
                           const float* __restrict__ g,  const float* __restrict__ be,
                           const float* __restrict__ W2, const float* __restrict__ b2,
                           float* __restrict__ out) {
    __shared__ float w1_s[4096];
    __shared__ float cct_s[1024];
    __shared__ float w2_s[64];
    __shared__ float b1_s[64], g_s[64], be_s[64];
    __shared__ float dens_s[4][64];
    int t = threadIdx.x;
    for (int i = t; i < 1024; i += 256) ((float4*)w1_s)[i] = ((const float4*)W1)[i];
    if (t < 256) ((float4*)cct_s)[t] = ((const float4*)cct_l)[t];
    if (t < 64) { b1_s[t] = b1[t]; g_s[t] = g[t]; be_s[t] = be[t]; w2_s[t] = W2[t]; }
    __syncthreads();

    int lane = t & 63, slot = t >> 6;
    int abase = blockIdx.x * 64;
    float b2v = b2[0];
#pragma unroll 1
    for (int gi = 0; gi < 16; gi++) {
        int atom = abase + gi * 4 + slot;
        float cr[32];
        const float4* cp = (const float4*)(co + (size_t)atom * 32);
#pragma unroll
        for (int q = 0; q < 8; q++) {
            float4 v = cp[q];
            cr[q * 4 + 0] = v.x; cr[q * 4 + 1] = v.y; cr[q * 4 + 2] = v.z; cr[q * 4 + 3] = v.w;
        }
        const float4* c0 = (const float4*)(cct_s + lane * 8);
        const float4* c1 = (const float4*)(cct_s + 512 + lane * 8);
        float4 ca0 = c0[0], ca1 = c0[1];
        float4 cb0 = c1[0], cb1 = c1[1];
        float dens = ccoef[(size_t)atom * 64 + lane];
        {
            float s = cr[0] * ca0.x + cr[1] * ca0.y + cr[2] * ca0.z + cr[3] * ca0.w
                    + cr[4] * ca1.x + cr[5] * ca1.y + cr[6] * ca1.z + cr[7] * ca1.w;
            dens += s * s;
        }
#pragma unroll
        for (int jj = 1; jj < 4; jj++) {
            const float* cj = cr + jj * 8;
            float s = cj[0] * cb0.x + cj[1] * cb0.y + cj[2] * cb0.z + cj[3] * cb0.w
                    + cj[4] * cb1.x + cj[5] * cb1.y + cj[6] * cb1.z + cj[7] * cb1.w;
            dens += s * s;
        }
        dens_s[slot][lane] = dens;
        __syncthreads();

        float h = b1_s[lane];
#pragma unroll 16
        for (int i = 0; i < 64; i++) h += dens_s[slot][i] * w1_s[i * 64 + lane];
        h = ln_silu(h, g_s[lane], be_s[lane]);
        float s = wred_sum(h * w2_s[lane]);
        if (lane == 0) {
            float mask = (spec[atom] >= 0) ? 1.f : 0.f;
            out[atom] = (s + b2v) * mask;
        }
        __syncthreads();
    }
}

extern "C" void kernel_launch(void* const* d_in, const int* in_sizes, int n_in,
                              void* d_out, int out_size, void* d_ws, size_t ws_size,
                              hipStream_t stream) {
    const float* cart   = (const float*)d_in[0];
    const int*   aidx   = (const int*)d_in[1];
    const int*   spec   = (const int*)d_in[2];
    const float* ccoeff = (const float*)d_in[4];
    const float* embn_W1 = (const float*)d_in[5];
    const float* embn_b1 = (const float*)d_in[6];
    const float* embn_g  = (const float*)d_in[7];
    const float* embn_be = (const float*)d_in[8];
    const float* embn_W2 = (const float*)d_in[9];
    const float* embn_b2 = (const float*)d_in[10];
    const float* embc_W1 = (const float*)d_in[11];
    const float* embc_b1 = (const float*)d_in[12];
    const float* embc_g  = (const float*)d_in[13];
    const float* embc_be = (const float*)d_in[14];
    const float* embc_W2 = (const float*)d_in[15];
    const float* embc_b2 = (const float*)d_in[16];
    const float* oc_W1 = (const float*)d_in[17];
    const float* oc_b1 = (const float*)d_in[18];
    const float* oc_g  = (const float*)d_in[19];
    const float* oc_be = (const float*)d_in[20];
    const float* oc_W2 = (const float*)d_in[21];
    const float* oc_b2 = (const float*)d_in[22];
    const float* out_W1 = (const float*)d_in[23];
    const float* out_b1 = (const float*)d_in[24];
    const float* out_g  = (const float*)d_in[25];
    const float* out_be = (const float*)d_in[26];
    const float* out_W2 = (const float*)d_in[27];
    const float* out_b2 = (const float*)d_in[28];

    float* outp = (float*)d_out;

    char* ws = (char*)d_ws;
    size_t off = 0;
    auto carve = [&](size_t bytes) { size_t o = off; off = (off + bytes + 255) & ~(size_t)255; return o; };
    float4* ang    = (float4*)(ws + carve((size_t)NPADC * 16));
    float4* rad2   = (float4*)(ws + carve((size_t)NPADC * 32));
    int*   keyv    = (int*)(ws + carve((size_t)NPADC * 4));
    int*   neigh   = (int*)(ws + carve((size_t)NPADC * 4));
    int*   plist   = (int*)(ws + carve((size_t)NPADC * 4));
    float* ccenter = (float*)(ws + carve((size_t)NATOMS * 64 * 4));
    float* co0     = (float*)(ws + carve((size_t)NATOMS * 32 * 4));
    float* cocur   = (float*)(ws + carve((size_t)NATOMS * 32 * 4));
    float* Sa      = (float*)(ws + carve((size_t)NATOMS * 8 * 4));
    float* Sb      = (float*)(ws + carve((size_t)NATOMS * 8 * 4));
    float* table   = (float*)(ws + carve((size_t)TBLN * 24 * 4));
    float* embc_W2t= (float*)(ws + carve(4096 * 4));
    float* oc_W2t  = (float*)(ws + carve(1536 * 4));
    float* cct     = (float*)(ws + carve(4096 * 4));
    int*   cnt     = (int*)(ws + carve((size_t)NATOMS * 4));
    int*   offs    = (int*)(ws + carve((size_t)(NATOMS + 1) * 4));
    int*   cursor  = (int*)(ws + carve((size_t)NATOMS * 4));

    hipMemsetAsync(cnt, 0, (size_t)NATOMS * 4, stream);
    hipMemsetAsync(plist, 0xFF, (size_t)NPADC * 4, stream);

    k_hist<<<NPAIRS / 256, 256, 0, stream>>>(aidx, cnt);
    k_scan<<<1, 1024, 0, stream>>>(cnt, offs, cursor);
    k_scatter<<<NPAIRS / 256, 256, 0, stream>>>(aidx, cursor, plist);

    k_prep<<<(9728 + 255) / 256, 256, 0, stream>>>(embc_W2, oc_W2, ccoeff,
                                                   embc_W2t, oc_W2t, cct);
    k_center<<<NATOMS / 4, 256, 0, stream>>>(spec, embc_W1, embc_b1, embc_g, embc_be,
                                             embc_W2t, embc_b2, ccenter);
    k_table<<<(TBLN + 3) / 4, 256, 0, stream>>>(embn_W1, embn_b1, embn_g, embn_be,
                                                embn_W2, embn_b2, table);

    k_pair2<<<NPADC / 256, 256, 0, stream>>>(cart, aidx, spec, table, plist, offs + NATOMS,
                                             outp, ang, rad2, keyv, neigh);

    // pass 0
    k_co<true><<<NATOMS / 4, 256, 0, stream>>>(offs, ang, rad2, keyv, table,
                                               nullptr, nullptr, nullptr, co0);
    k_dmlp<false><<<NATOMS / 64, 256, 0, stream>>>(co0, ccenter, cct + 0 * 1024,
                                                   oc_W1 + 0 * 4096, oc_b1 + 0 * 64,
                                                   oc_g + 0 * 64, oc_be + 0 * 64,
                                                   oc_W2t + 0 * 512, oc_b2 + 0 * 8,
                                                   nullptr, Sa);
    // pass 1
    k_co<false><<<NATOMS / 4, 256, 0, stream>>>(offs, ang, rad2, nullptr, nullptr,
                                                neigh, Sa, co0, cocur);
    k_dmlp<true><<<NATOMS / 64, 256, 0, stream>>>(cocur, ccenter, cct + 1 * 1024,
                                                  oc_W1 + 1 * 4096, oc_b1 + 1 * 64,
                                                  oc_g + 1 * 64, oc_be + 1 * 64,
                                                  oc_W2t + 1 * 512, oc_b2 + 1 * 8,
                                                  Sa, Sb);
    // pass 2
    k_co<false><<<NATOMS / 4, 256, 0, stream>>>(offs, ang, rad2, nullptr, nullptr,
                                                neigh, Sb, co0, cocur);
    k_dmlp<true><<<NATOMS / 64, 256, 0, stream>>>(cocur, ccenter, cct + 2 * 1024,
                                                  oc_W1 + 2 * 4096, oc_b1 + 2 * 64,
                                                  oc_g + 2 * 64, oc_be + 2 * 64,
                                                  oc_W2t + 2 * 512, oc_b2 + 2 * 8,
                                                  Sb, Sa);
    // final
    k_co<false><<<NATOMS / 4, 256, 0, stream>>>(offs, ang, rad2, nullptr, nullptr,
                                                neigh, Sa, co0, cocur);
    k_dmlp_out<<<NATOMS / 64, 256, 0, stream>>>(cocur, ccenter, cct + 3 * 1024, spec,
                                                out_W1, out_b1, out_g, out_be,
                                                out_W2, out_b2, outp + (size_t)NPAIRS * 3);
}

// Round 7
// 258.609 us; speedup vs baseline: 1.3286x; 1.3286x over previous
//
#include <hip/hip_runtime.h>
#include <math.h>

#define NWAVE   8
#define NATOMS  16384
#define NPAIRS  524288
#define NSPEC   117
#define TBLN    (NSPEC * NSPEC)
#define NPADC   (NPAIRS + NATOMS * 8)   // 655360 max padded slots
#define APB     16                      // atoms per block in pass kernels

// ---------- helpers ----------
__device__ __forceinline__ float wred_sum(float v) {
#pragma unroll
    for (int o = 1; o < 64; o <<= 1) v += __shfl_xor(v, o, 64);
    return v;
}

__device__ __forceinline__ float ln_silu(float h, float gg, float bb) {
    float m = wred_sum(h) * (1.f / 64.f);
    float c = h - m;
    float v = wred_sum(c * c) * (1.f / 64.f);
    float y = c * rsqrtf(v + 1e-5f) * gg + bb;
    return y / (1.f + expf(-y));
}

__device__ __forceinline__ float dot4(float4 a, float4 b) {
    return a.x * b.x + a.y * b.y + a.z * b.z + a.w * b.w;
}

// ---------- CSR build (padded to multiple of 8 per atom) ----------
__global__ void k_hist(const int* __restrict__ ai0, int* __restrict__ cnt,
                       int* __restrict__ plist) {
    int p = blockIdx.x * 256 + threadIdx.x;
    if (p < NPAIRS) atomicAdd(&cnt[ai0[p]], 1);
    for (int q = p; q < NPADC; q += NPAIRS) plist[q] = -1;
}

__global__ void k_scan(const int* __restrict__ cnt, int* __restrict__ offs,
                       int* __restrict__ cursor) {
    __shared__ int sums[1024];
    int t = threadIdx.x;
    int base = t * 16;
    int v[16];
    int s = 0;
#pragma unroll
    for (int u = 0; u < 16; u++) { v[u] = (cnt[base + u] + 7) & ~7; s += v[u]; }
    sums[t] = s;
    __syncthreads();
    for (int d = 1; d < 1024; d <<= 1) {
        int x = (t >= d) ? sums[t - d] : 0;
        __syncthreads();
        sums[t] += x;
        __syncthreads();
    }
    int run = (t == 0) ? 0 : sums[t - 1];
#pragma unroll
    for (int u = 0; u < 16; u++) {
        offs[base + u] = run;
        cursor[base + u] = run;
        run += v[u];
    }
    if (t == 1023) offs[NATOMS] = run;
}

__global__ void k_scatter(const int* __restrict__ ai0, int* __restrict__ cursor,
                          int* __restrict__ plist) {
    int p = blockIdx.x * 256 + threadIdx.x;
    if (p < NPAIRS) {
        int pos = atomicAdd(&cursor[ai0[p]], 1);
        plist[pos] = p;
    }
}

// ---------- embc MLP per atom ----------
__global__ void k_center(const int* __restrict__ spec,
                         const float* __restrict__ W1, const float* __restrict__ b1,
                         const float* __restrict__ g,  const float* __restrict__ be,
                         const float* __restrict__ W2, const float* __restrict__ b2,
                         float* __restrict__ ccoef) {
    __shared__ float h_s[4][64];
    int lane = threadIdx.x & 63, slot = threadIdx.x >> 6;
    int atom = blockIdx.x * 4 + slot;
    int s = spec[atom] + 1;
    float h = W1[s * 64 + lane] + b1[lane];
    h = ln_silu(h, g[lane], be[lane]);
    h_s[slot][lane] = h;
    __syncthreads();
    float o = b2[lane];
#pragma unroll 8
    for (int i = 0; i < 64; i++) o += h_s[slot][i] * W2[i * 64 + lane];
    ccoef[atom * 64 + lane] = o;
}

// ---------- embn MLP per unique species pair ----------
__global__ void k_table(const float* __restrict__ W1, const float* __restrict__ b1,
                        const float* __restrict__ g,  const float* __restrict__ be,
                        const float* __restrict__ W2, const float* __restrict__ b2,
                        float* __restrict__ table) {
    __shared__ float h_s[4][64];
    int lane = threadIdx.x & 63, slot = threadIdx.x >> 6;
    int key = blockIdx.x * 4 + slot;
    int kk = (key < TBLN) ? key : 0;
    int s0 = kk / NSPEC + 1, s1 = kk % NSPEC + 1;
    float h = W1[s0 * 64 + lane] + W1[s1 * 64 + lane] + b1[lane];
    h = ln_silu(h, g[lane], be[lane]);
    h_s[slot][lane] = h;
    __syncthreads();
    if (lane < 24 && key < TBLN) {
        float o = b2[lane];
#pragma unroll 8
        for (int i = 0; i < 64; i++) o += h_s[slot][i] * W2[i * 24 + lane];
        table[key * 24 + lane] = o;
    }
}

// ---------- per-pair: transposed streams ----------
__global__ void k_pair2(const float* __restrict__ cart, const int* __restrict__ aidx,
                        const int* __restrict__ spec,  const float* __restrict__ table,
                        const int* __restrict__ plist, const int* __restrict__ total_p,
                        float* __restrict__ dist_out, float* __restrict__ ang_t,
                        float* __restrict__ rad_t,    int* __restrict__ keyv,
                        int* __restrict__ neigh) {
    int pos = blockIdx.x * 256 + threadIdx.x;
    if (pos >= total_p[0]) return;
    int p = plist[pos];
    if (p < 0) {
#pragma unroll
        for (int j = 0; j < 4; j++) ang_t[(size_t)j * NPADC + pos] = 0.f;
#pragma unroll
        for (int k = 0; k < 8; k++) rad_t[(size_t)k * NPADC + pos] = 0.f;
        keyv[pos] = 0;
        neigh[pos] = 0;
        return;
    }
    int i0 = aidx[p];
    int i1 = aidx[NPAIRS + p];
    float dv0 = cart[i0 * 3 + 0] - cart[i1 * 3 + 0];
    float dv1 = cart[i0 * 3 + 1] - cart[i1 * 3 + 1];
    float dv2 = cart[i0 * 3 + 2] - cart[i1 * 3 + 2];
    float d = sqrtf(dv0 * dv0 + dv1 * dv1 + dv2 * dv2);
    dist_out[(size_t)p * 3 + 0] = dv0;
    dist_out[(size_t)p * 3 + 1] = dv1;
    dist_out[(size_t)p * 3 + 2] = dv2;

    int key = spec[i0] * NSPEC + spec[i1];
    const float4* ne = (const float4*)(table + (size_t)key * 24);
    float4 al_a = ne[2], al_b = ne[3];
    float4 mu_a = ne[4], mu_b = ne[5];

    float cth = cosf(d * (float)(M_PI / 4.0));
    float t0 = 0.5f * cth + 0.5f;
    float fc = t0 * t0;
    ang_t[(size_t)0 * NPADC + pos] = fc;
    ang_t[(size_t)1 * NPADC + pos] = dv0 * fc;
    ang_t[(size_t)2 * NPADC + pos] = dv1 * fc;
    ang_t[(size_t)3 * NPADC + pos] = dv2 * fc;

    float r[8];
    float t;
    t = al_a.x * (d - mu_a.x); r[0] = expf(-t * t);
    t = al_a.y * (d - mu_a.y); r[1] = expf(-t * t);
    t = al_a.z * (d - mu_a.z); r[2] = expf(-t * t);
    t = al_a.w * (d - mu_a.w); r[3] = expf(-t * t);
    t = al_b.x * (d - mu_b.x); r[4] = expf(-t * t);
    t = al_b.y * (d - mu_b.y); r[5] = expf(-t * t);
    t = al_b.z * (d - mu_b.z); r[6] = expf(-t * t);
    t = al_b.w * (d - mu_b.w); r[7] = expf(-t * t);
#pragma unroll
    for (int k = 0; k < 8; k++) rad_t[(size_t)k * NPADC + pos] = r[k];
    keyv[pos] = key;
    neigh[pos] = i1;
}

// ---------- fused pass: gather co -> contraction -> MLP. APB atoms/block ----------
// PASS0: gather it0 via keyv/table, write co0. else: gather S_in[neigh], add co0.
// FINAL: out-MLP -> scalar output. ACC (= !PASS0 && !FINAL): S_out = o + S_in[atom].
template <bool PASS0, bool FINAL>
__global__ __launch_bounds__(256, 4)
void k_pass(const int* __restrict__ offs,
            const float* __restrict__ ang_t, const float* __restrict__ rad_t,
            const int* __restrict__ keyv,  const float* __restrict__ table,
            const int* __restrict__ neigh, const float* __restrict__ S_in,
            float* __restrict__ co0,       const float* __restrict__ ccenter,
            const float* __restrict__ cc_g,
            const float* __restrict__ W1,  const float* __restrict__ b1,
            const float* __restrict__ g,   const float* __restrict__ be,
            const float* __restrict__ W2,  const float* __restrict__ b2,
            const int* __restrict__ spec,  float* __restrict__ dst) {
    __shared__ float w1_s[4096];     // raw [i][o]
    __shared__ float cc_s[1024];     // raw [row][k][m]
    __shared__ float w2t_s[512];     // [o][i] (oc) ; first 64 = W2 vec (final)
    __shared__ float b1_s[64], g_s[64], be_s[64], b2_s[8];
    __shared__ float co_s[APB][32];
    __shared__ float dens_s[4][64], h_s[4][64];

    const int t = threadIdx.x, lane = t & 63, wv = t >> 6;
    const int abase = blockIdx.x * APB;

    // ---- stage weights ----
    for (int i = t; i < 1024; i += 256) ((float4*)w1_s)[i] = ((const float4*)W1)[i];
    if (t < 256) ((float4*)cc_s)[t] = ((const float4*)cc_g)[t];
    if (FINAL) {
        if (t < 64) w2t_s[t] = W2[t];
        if (t == 64) b2_s[0] = b2[0];
    } else {
        if (t < 256) {  // transpose W2 (64x8) -> w2t (8x64), two elems per thread
            int i = t >> 2, o0 = (t & 3) * 2;
            w2t_s[(o0 + 0) * 64 + i] = W2[i * 8 + o0 + 0];
            w2t_s[(o0 + 1) * 64 + i] = W2[i * 8 + o0 + 1];
        }
        if (t >= 256 - 8) b2_s[t - 248] = b2[t - 248];
    }
    if (t < 64) { b1_s[t] = b1[t]; g_s[t] = g[t]; be_s[t] = be[t]; }

    // ---- gather: half-wave per local atom ----
    for (int la = wv * 2 + (lane >> 5); la < APB; la += 8) {
        int atom = abase + la;
        int start = offs[atom], end = offs[atom + 1];
        int jk = lane & 31, j = jk >> 3, k = jk & 7;
        const float* aj = ang_t + (size_t)j * NPADC + start;
        const float* rk = rad_t + (size_t)k * NPADC + start;
        float acc = 0.f;
        if (PASS0) {
            const int* kb = keyv + start;
#pragma unroll 2
            for (int q = 0; q < end - start; q += 4) {
                float4 av = *(const float4*)(aj + q);
                float4 rv = *(const float4*)(rk + q);
                int4 k4 = *(const int4*)(kb + q);
                acc += av.x * rv.x * table[(size_t)k4.x * 24 + k]
                     + av.y * rv.y * table[(size_t)k4.y * 24 + k]
                     + av.z * rv.z * table[(size_t)k4.z * 24 + k]
                     + av.w * rv.w * table[(size_t)k4.w * 24 + k];
            }
            co0[(size_t)atom * 32 + jk] = acc;
            co_s[la][jk] = acc;
        } else {
            const int* nbp = neigh + start;
#pragma unroll 2
            for (int q = 0; q < end - start; q += 4) {
                float4 av = *(const float4*)(aj + q);
                float4 rv = *(const float4*)(rk + q);
                int4 n4 = *(const int4*)(nbp + q);
                acc += av.x * rv.x * S_in[(size_t)n4.x * 8 + k]
                     + av.y * rv.y * S_in[(size_t)n4.y * 8 + k]
                     + av.z * rv.z * S_in[(size_t)n4.z * 8 + k]
                     + av.w * rv.w * S_in[(size_t)n4.w * 8 + k];
            }
            co_s[la][jk] = acc + co0[(size_t)atom * 32 + jk];
        }
    }
    __syncthreads();   // co + staged weights ready

    // ---- contraction + MLP: wave per atom ----
#pragma unroll 1
    for (int la = wv; la < APB; la += 4) {
        int atom = abase + la;
        float dens = ccenter[(size_t)atom * 64 + lane];
#pragma unroll
        for (int jj = 0; jj < 4; jj++) {
            int row = jj ? 1 : 0;
            float s = 0.f;
#pragma unroll
            for (int kk = 0; kk < 8; kk++)
                s += co_s[la][jj * 8 + kk] * cc_s[row * 512 + kk * 64 + lane];
            dens += s * s;
        }
        dens_s[wv][lane] = dens;
        __syncthreads();

        float h = b1_s[lane];
        const float4* dp = (const float4*)dens_s[wv];
#pragma unroll
        for (int q = 0; q < 16; q++) {
            float4 dv = dp[q];
            h += dv.x * w1_s[(q * 4 + 0) * 64 + lane]
               + dv.y * w1_s[(q * 4 + 1) * 64 + lane]
               + dv.z * w1_s[(q * 4 + 2) * 64 + lane]
               + dv.w * w1_s[(q * 4 + 3) * 64 + lane];
        }
        h = ln_silu(h, g_s[lane], be_s[lane]);

        if (FINAL) {
            float s = wred_sum(h * w2t_s[lane]);
            if (lane == 0) {
                float mask = (spec[atom] >= 0) ? 1.f : 0.f;
                dst[atom] = (s + b2_s[0]) * mask;
            }
            __syncthreads();
        } else {
            h_s[wv][lane] = h;
            __syncthreads();
            int o = lane >> 3, seg = lane & 7;
            const float4* w2p = (const float4*)(w2t_s + o * 64 + seg * 8);
            const float4* hp  = (const float4*)(&h_s[wv][seg * 8]);
            float part = dot4(w2p[0], hp[0]) + dot4(w2p[1], hp[1]);
            part += __shfl_xor(part, 1, 64);
            part += __shfl_xor(part, 2, 64);
            part += __shfl_xor(part, 4, 64);
            if (seg == 0) {
                float val = part + b2_s[o];
                if (!PASS0) val += S_in[(size_t)atom * 8 + o];
                dst[(size_t)atom * 8 + o] = val;
            }
        }
    }
}

extern "C" void kernel_launch(void* const* d_in, const int* in_sizes, int n_in,
                              void* d_out, int out_size, void* d_ws, size_t ws_size,
                              hipStream_t stream) {
    const float* cart   = (const float*)d_in[0];
    const int*   aidx   = (const int*)d_in[1];
    const int*   spec   = (const int*)d_in[2];
    const float* ccoeff = (const float*)d_in[4];
    const float* embn_W1 = (const float*)d_in[5];
    const float* embn_b1 = (const float*)d_in[6];
    const float* embn_g  = (const float*)d_in[7];
    const float* embn_be = (const float*)d_in[8];
    const float* embn_W2 = (const float*)d_in[9];
    const float* embn_b2 = (const float*)d_in[10];
    const float* embc_W1 = (const float*)d_in[11];
    const float* embc_b1 = (const float*)d_in[12];
    const float* embc_g  = (const float*)d_in[13];
    const float* embc_be = (const float*)d_in[14];
    const float* embc_W2 = (const float*)d_in[15];
    const float* embc_b2 = (const float*)d_in[16];
    const float* oc_W1 = (const float*)d_in[17];
    const float* oc_b1 = (const float*)d_in[18];
    const float* oc_g  = (const float*)d_in[19];
    const float* oc_be = (const float*)d_in[20];
    const float* oc_W2 = (const float*)d_in[21];
    const float* oc_b2 = (const float*)d_in[22];
    const float* out_W1 = (const float*)d_in[23];
    const float* out_b1 = (const float*)d_in[24];
    const float* out_g  = (const float*)d_in[25];
    const float* out_be = (const float*)d_in[26];
    const float* out_W2 = (const float*)d_in[27];
    const float* out_b2 = (const float*)d_in[28];

    float* outp = (float*)d_out;

    char* ws = (char*)d_ws;
    size_t off = 0;
    auto carve = [&](size_t bytes) { size_t o = off; off = (off + bytes + 255) & ~(size_t)255; return o; };
    float* ang_t   = (float*)(ws + carve((size_t)4 * NPADC * 4));
    float* rad_t   = (float*)(ws + carve((size_t)8 * NPADC * 4));
    int*   keyv    = (int*)(ws + carve((size_t)NPADC * 4));
    int*   neigh   = (int*)(ws + carve((size_t)NPADC * 4));
    int*   plist   = (int*)(ws + carve((size_t)NPADC * 4));
    float* ccenter = (float*)(ws + carve((size_t)NATOMS * 64 * 4));
    float* co0     = (float*)(ws + carve((size_t)NATOMS * 32 * 4));
    float* Sa      = (float*)(ws + carve((size_t)NATOMS * 8 * 4));
    float* Sb      = (float*)(ws + carve((size_t)NATOMS * 8 * 4));
    float* table   = (float*)(ws + carve((size_t)TBLN * 24 * 4));
    int*   cnt     = (int*)(ws + carve((size_t)NATOMS * 4));
    int*   offs    = (int*)(ws + carve((size_t)(NATOMS + 1) * 4));
    int*   cursor  = (int*)(ws + carve((size_t)NATOMS * 4));

    hipMemsetAsync(cnt, 0, (size_t)NATOMS * 4, stream);
    k_hist<<<NPAIRS / 256, 256, 0, stream>>>(aidx, cnt, plist);
    k_scan<<<1, 1024, 0, stream>>>(cnt, offs, cursor);
    k_scatter<<<NPAIRS / 256, 256, 0, stream>>>(aidx, cursor, plist);

    k_table<<<(TBLN + 3) / 4, 256, 0, stream>>>(embn_W1, embn_b1, embn_g, embn_be,
                                                embn_W2, embn_b2, table);
    k_center<<<NATOMS / 4, 256, 0, stream>>>(spec, embc_W1, embc_b1, embc_g, embc_be,
                                             embc_W2, embc_b2, ccenter);

    k_pair2<<<NPADC / 256, 256, 0, stream>>>(cart, aidx, spec, table, plist, offs + NATOMS,
                                             outp, ang_t, rad_t, keyv, neigh);

    // pass 0: co0 + oc0 -> Sa
    k_pass<true, false><<<NATOMS / APB, 256, 0, stream>>>(
        offs, ang_t, rad_t, keyv, table, neigh, nullptr, co0, ccenter,
        ccoeff + 0 * 1024, oc_W1 + 0 * 4096, oc_b1 + 0 * 64, oc_g + 0 * 64,
        oc_be + 0 * 64, oc_W2 + 0 * 512, oc_b2 + 0 * 8, spec, Sa);
    // pass 1: S=Sa -> Sb (= Sa + oc1)
    k_pass<false, false><<<NATOMS / APB, 256, 0, stream>>>(
        offs, ang_t, rad_t, keyv, table, neigh, Sa, co0, ccenter,
        ccoeff + 1 * 1024, oc_W1 + 1 * 4096, oc_b1 + 1 * 64, oc_g + 1 * 64,
        oc_be + 1 * 64, oc_W2 + 1 * 512, oc_b2 + 1 * 8, spec, Sb);
    // pass 2: S=Sb -> Sa (= Sb + oc2)
    k_pass<false, false><<<NATOMS / APB, 256, 0, stream>>>(
        offs, ang_t, rad_t, keyv, table, neigh, Sb, co0, ccenter,
        ccoeff + 2 * 1024, oc_W1 + 2 * 4096, oc_b1 + 2 * 64, oc_g + 2 * 64,
        oc_be + 2 * 64, oc_W2 + 2 * 512, oc_b2 + 2 * 8, spec, Sa);
    // final: S=Sa -> output
    k_pass<false, true><<<NATOMS / APB, 256, 0, stream>>>(
        offs, ang_t, rad_t, keyv, table, neigh, Sa, co0, ccenter,
        ccoeff + 3 * 1024, out_W1, out_b1, out_g, out_be,
        out_W2, out_b2, spec, outp + (size_t)NPAIRS * 3);
}

// Round 8
// 257.450 us; speedup vs baseline: 1.3346x; 1.0045x over previous
//
#include <hip/hip_runtime.h>
#include <math.h>

#define NWAVE   8
#define NATOMS  16384
#define NPAIRS  524288
#define NSPEC   117
#define TBLN    (NSPEC * NSPEC)
#define NPADC   (NPAIRS + NATOMS * 8)   // 655360 max padded slots
#define APB     32                      // atoms per block in pass kernels
#define CBLK    (NATOMS / 4)            // center blocks in k_emb
#define TBLK    ((TBLN + 3) / 4)        // table blocks in k_emb

typedef unsigned short ushort_t;
typedef unsigned int uint_t;

// ---------- helpers ----------
__device__ __forceinline__ float wred_sum(float v) {
#pragma unroll
    for (int o = 1; o < 64; o <<= 1) v += __shfl_xor(v, o, 64);
    return v;
}

__device__ __forceinline__ float ln_silu(float h, float gg, float bb) {
    float m = wred_sum(h) * (1.f / 64.f);
    float c = h - m;
    float v = wred_sum(c * c) * (1.f / 64.f);
    float y = c * rsqrtf(v + 1e-5f) * gg + bb;
    return y / (1.f + expf(-y));
}

__device__ __forceinline__ float dot4(float4 a, float4 b) {
    return a.x * b.x + a.y * b.y + a.z * b.z + a.w * b.w;
}

__device__ __forceinline__ ushort_t f2bf(float x) {
    uint_t u = __float_as_uint(x);
    u += 0x7FFF + ((u >> 16) & 1);
    return (ushort_t)(u >> 16);
}
__device__ __forceinline__ float bf2f(ushort_t s) {
    return __uint_as_float(((uint_t)s) << 16);
}

// ---------- k_hist: cnt histogram + dist_vec output + plist init ----------
__global__ void k_hist(const int* __restrict__ aidx, const float* __restrict__ cart,
                       int* __restrict__ cnt, int* __restrict__ plist,
                       float* __restrict__ dist_out) {
    int p = blockIdx.x * 256 + threadIdx.x;
    if (p < NPAIRS) {
        atomicAdd(&cnt[aidx[p]], 1);
        int i0 = aidx[p];
        int i1 = aidx[NPAIRS + p];
        float dv0 = cart[i0 * 3 + 0] - cart[i1 * 3 + 0];
        float dv1 = cart[i0 * 3 + 1] - cart[i1 * 3 + 1];
        float dv2 = cart[i0 * 3 + 2] - cart[i1 * 3 + 2];
        dist_out[(size_t)p * 3 + 0] = dv0;
        dist_out[(size_t)p * 3 + 1] = dv1;
        dist_out[(size_t)p * 3 + 2] = dv2;
    }
    for (int q = p; q < NPADC; q += NPAIRS) plist[q] = -1;
}

__global__ void k_scan(const int* __restrict__ cnt, int* __restrict__ offs,
                       int* __restrict__ cursor) {
    __shared__ int sums[1024];
    int t = threadIdx.x;
    int base = t * 16;
    int v[16];
    int s = 0;
#pragma unroll
    for (int u = 0; u < 16; u++) { v[u] = (cnt[base + u] + 7) & ~7; s += v[u]; }
    sums[t] = s;
    __syncthreads();
    for (int d = 1; d < 1024; d <<= 1) {
        int x = (t >= d) ? sums[t - d] : 0;
        __syncthreads();
        sums[t] += x;
        __syncthreads();
    }
    int run = (t == 0) ? 0 : sums[t - 1];
#pragma unroll
    for (int u = 0; u < 16; u++) {
        offs[base + u] = run;
        cursor[base + u] = run;
        run += v[u];
    }
    if (t == 1023) offs[NATOMS] = run;
}

__global__ void k_scatter(const int* __restrict__ ai0, int* __restrict__ cursor,
                          int* __restrict__ plist) {
    int p = blockIdx.x * 256 + threadIdx.x;
    if (p < NPAIRS) {
        int pos = atomicAdd(&cursor[ai0[p]], 1);
        plist[pos] = p;
    }
}

// ---------- k_emb: center MLP (blocks [0,CBLK)) + table MLP (blocks [CBLK,CBLK+TBLK)) ----------
__global__ void k_emb(const int* __restrict__ spec,
                      const float* __restrict__ cW1, const float* __restrict__ cb1,
                      const float* __restrict__ cg,  const float* __restrict__ cbe,
                      const float* __restrict__ cW2, const float* __restrict__ cb2,
                      float* __restrict__ ccoef,
                      const float* __restrict__ nW1, const float* __restrict__ nb1,
                      const float* __restrict__ ng,  const float* __restrict__ nbe,
                      const float* __restrict__ nW2, const float* __restrict__ nb2,
                      float* __restrict__ table) {
    __shared__ float h_s[4][64];
    int lane = threadIdx.x & 63, slot = threadIdx.x >> 6;
    if (blockIdx.x < CBLK) {
        int atom = blockIdx.x * 4 + slot;
        int s = spec[atom] + 1;
        float h = cW1[s * 64 + lane] + cb1[lane];
        h = ln_silu(h, cg[lane], cbe[lane]);
        h_s[slot][lane] = h;
        __syncthreads();
        float o = cb2[lane];
#pragma unroll 8
        for (int i = 0; i < 64; i++) o += h_s[slot][i] * cW2[i * 64 + lane];
        ccoef[atom * 64 + lane] = o;
    } else {
        int key = (blockIdx.x - CBLK) * 4 + slot;
        int kk = (key < TBLN) ? key : 0;
        int s0 = kk / NSPEC + 1, s1 = kk % NSPEC + 1;
        float h = nW1[s0 * 64 + lane] + nW1[s1 * 64 + lane] + nb1[lane];
        h = ln_silu(h, ng[lane], nbe[lane]);
        h_s[slot][lane] = h;
        __syncthreads();
        if (lane < 24 && key < TBLN) {
            float o = nb2[lane];
#pragma unroll 8
            for (int i = 0; i < 64; i++) o += h_s[slot][i] * nW2[i * 24 + lane];
            table[key * 24 + lane] = o;
        }
    }
}

// ---------- per-pair: bf16 planar streams ----------
__global__ void k_pair2(const float* __restrict__ cart, const int* __restrict__ aidx,
                        const int* __restrict__ spec,  const float* __restrict__ table,
                        const int* __restrict__ plist, const int* __restrict__ total_p,
                        ushort_t* __restrict__ ang16,  ushort_t* __restrict__ rad16,
                        int* __restrict__ keyv,        int* __restrict__ neigh) {
    int pos = blockIdx.x * 256 + threadIdx.x;
    if (pos >= total_p[0]) return;
    int p = plist[pos];
    if (p < 0) {
#pragma unroll
        for (int j = 0; j < 4; j++) ang16[(size_t)j * NPADC + pos] = 0;
#pragma unroll
        for (int k = 0; k < 8; k++) rad16[(size_t)k * NPADC + pos] = 0;
        keyv[pos] = 0;
        neigh[pos] = 0;
        return;
    }
    int i0 = aidx[p];
    int i1 = aidx[NPAIRS + p];
    float dv0 = cart[i0 * 3 + 0] - cart[i1 * 3 + 0];
    float dv1 = cart[i0 * 3 + 1] - cart[i1 * 3 + 1];
    float dv2 = cart[i0 * 3 + 2] - cart[i1 * 3 + 2];
    float d = sqrtf(dv0 * dv0 + dv1 * dv1 + dv2 * dv2);

    int key = spec[i0] * NSPEC + spec[i1];
    const float4* ne = (const float4*)(table + (size_t)key * 24);
    float4 al_a = ne[2], al_b = ne[3];
    float4 mu_a = ne[4], mu_b = ne[5];

    float cth = cosf(d * (float)(M_PI / 4.0));
    float t0 = 0.5f * cth + 0.5f;
    float fc = t0 * t0;
    ang16[(size_t)0 * NPADC + pos] = f2bf(fc);
    ang16[(size_t)1 * NPADC + pos] = f2bf(dv0 * fc);
    ang16[(size_t)2 * NPADC + pos] = f2bf(dv1 * fc);
    ang16[(size_t)3 * NPADC + pos] = f2bf(dv2 * fc);

    float r[8];
    float t;
    t = al_a.x * (d - mu_a.x); r[0] = expf(-t * t);
    t = al_a.y * (d - mu_a.y); r[1] = expf(-t * t);
    t = al_a.z * (d - mu_a.z); r[2] = expf(-t * t);
    t = al_a.w * (d - mu_a.w); r[3] = expf(-t * t);
    t = al_b.x * (d - mu_b.x); r[4] = expf(-t * t);
    t = al_b.y * (d - mu_b.y); r[5] = expf(-t * t);
    t = al_b.z * (d - mu_b.z); r[6] = expf(-t * t);
    t = al_b.w * (d - mu_b.w); r[7] = expf(-t * t);
#pragma unroll
    for (int k = 0; k < 8; k++) rad16[(size_t)k * NPADC + pos] = f2bf(r[k]);
    keyv[pos] = key;
    neigh[pos] = i1;
}

// ---------- fused pass: gather co -> contraction -> MLP. APB atoms/block ----------
template <bool PASS0, bool FINAL>
__global__ __launch_bounds__(256, 4)
void k_pass(const int* __restrict__ offs,
            const ushort_t* __restrict__ ang16, const ushort_t* __restrict__ rad16,
            const int* __restrict__ keyv,  const float* __restrict__ table,
            const int* __restrict__ neigh, const float* __restrict__ S_in,
            float* __restrict__ co0,       const float* __restrict__ ccenter,
            const float* __restrict__ cc_g,
            const float* __restrict__ W1,  const float* __restrict__ b1,
            const float* __restrict__ g,   const float* __restrict__ be,
            const float* __restrict__ W2,  const float* __restrict__ b2,
            const int* __restrict__ spec,  float* __restrict__ dst) {
    __shared__ float w1_s[4096];     // raw [i][o]
    __shared__ float cc_s[1024];     // raw [row][k][m]
    __shared__ float w2t_s[512];     // [o][i] (oc) ; first 64 = W2 vec (final)
    __shared__ float b1_s[64], g_s[64], be_s[64], b2_s[8];
    __shared__ float co_s[APB][32];
    __shared__ float dens_s[4][64], h_s[4][64];

    const int t = threadIdx.x, lane = t & 63, wv = t >> 6;
    const int abase = blockIdx.x * APB;

    // ---- stage weights ----
    for (int i = t; i < 1024; i += 256) ((float4*)w1_s)[i] = ((const float4*)W1)[i];
    if (t < 256) ((float4*)cc_s)[t] = ((const float4*)cc_g)[t];
    if (FINAL) {
        if (t < 64) w2t_s[t] = W2[t];
        if (t == 64) b2_s[0] = b2[0];
    } else {
        if (t < 256) {  // transpose W2 (64x8) -> w2t (8x64)
            int i = t >> 2, o0 = (t & 3) * 2;
            w2t_s[(o0 + 0) * 64 + i] = W2[i * 8 + o0 + 0];
            w2t_s[(o0 + 1) * 64 + i] = W2[i * 8 + o0 + 1];
        }
        if (t >= 256 - 8) b2_s[t - 248] = b2[t - 248];
    }
    if (t < 64) { b1_s[t] = b1[t]; g_s[t] = g[t]; be_s[t] = be[t]; }

    // ---- gather: half-wave per local atom ----
    for (int la = wv * 2 + (lane >> 5); la < APB; la += 8) {
        int atom = abase + la;
        int start = offs[atom], end = offs[atom + 1];
        int jk = lane & 31, j = jk >> 3, k = jk & 7;
        const ushort_t* aj = ang16 + (size_t)j * NPADC + start;
        const ushort_t* rk = rad16 + (size_t)k * NPADC + start;
        float acc = 0.f;
        if (PASS0) {
            const int* kb = keyv + start;
#pragma unroll 2
            for (int q = 0; q < end - start; q += 4) {
                ushort4 a4 = *(const ushort4*)(aj + q);
                ushort4 r4 = *(const ushort4*)(rk + q);
                int4 k4 = *(const int4*)(kb + q);
                acc += bf2f(a4.x) * bf2f(r4.x) * table[(size_t)k4.x * 24 + k]
                     + bf2f(a4.y) * bf2f(r4.y) * table[(size_t)k4.y * 24 + k]
                     + bf2f(a4.z) * bf2f(r4.z) * table[(size_t)k4.z * 24 + k]
                     + bf2f(a4.w) * bf2f(r4.w) * table[(size_t)k4.w * 24 + k];
            }
            co0[(size_t)atom * 32 + jk] = acc;
            co_s[la][jk] = acc;
        } else {
            const int* nbp = neigh + start;
#pragma unroll 2
            for (int q = 0; q < end - start; q += 4) {
                ushort4 a4 = *(const ushort4*)(aj + q);
                ushort4 r4 = *(const ushort4*)(rk + q);
                int4 n4 = *(const int4*)(nbp + q);
                acc += bf2f(a4.x) * bf2f(r4.x) * S_in[(size_t)n4.x * 8 + k]
                     + bf2f(a4.y) * bf2f(r4.y) * S_in[(size_t)n4.y * 8 + k]
                     + bf2f(a4.z) * bf2f(r4.z) * S_in[(size_t)n4.z * 8 + k]
                     + bf2f(a4.w) * bf2f(r4.w) * S_in[(size_t)n4.w * 8 + k];
            }
            co_s[la][jk] = acc + co0[(size_t)atom * 32 + jk];
        }
    }
    __syncthreads();   // co + staged weights ready

    // ---- contraction + MLP: wave per atom ----
#pragma unroll 1
    for (int la = wv; la < APB; la += 4) {
        int atom = abase + la;
        float dens = ccenter[(size_t)atom * 64 + lane];
#pragma unroll
        for (int jj = 0; jj < 4; jj++) {
            int row = jj ? 1 : 0;
            float s = 0.f;
#pragma unroll
            for (int kk = 0; kk < 8; kk++)
                s += co_s[la][jj * 8 + kk] * cc_s[row * 512 + kk * 64 + lane];
            dens += s * s;
        }
        dens_s[wv][lane] = dens;
        __syncthreads();

        float h = b1_s[lane];
        const float4* dp = (const float4*)dens_s[wv];
#pragma unroll
        for (int q = 0; q < 16; q++) {
            float4 dv = dp[q];
            h += dv.x * w1_s[(q * 4 + 0) * 64 + lane]
               + dv.y * w1_s[(q * 4 + 1) * 64 + lane]
               + dv.z * w1_s[(q * 4 + 2) * 64 + lane]
               + dv.w * w1_s[(q * 4 + 3) * 64 + lane];
        }
        h = ln_silu(h, g_s[lane], be_s[lane]);

        if (FINAL) {
            float s = wred_sum(h * w2t_s[lane]);
            if (lane == 0) {
                float mask = (spec[atom] >= 0) ? 1.f : 0.f;
                dst[atom] = (s + b2_s[0]) * mask;
            }
            __syncthreads();
        } else {
            h_s[wv][lane] = h;
            __syncthreads();
            int o = lane >> 3, seg = lane & 7;
            const float4* w2p = (const float4*)(w2t_s + o * 64 + seg * 8);
            const float4* hp  = (const float4*)(&h_s[wv][seg * 8]);
            float part = dot4(w2p[0], hp[0]) + dot4(w2p[1], hp[1]);
            part += __shfl_xor(part, 1, 64);
            part += __shfl_xor(part, 2, 64);
            part += __shfl_xor(part, 4, 64);
            if (seg == 0) {
                float val = part + b2_s[o];
                if (!PASS0) val += S_in[(size_t)atom * 8 + o];
                dst[(size_t)atom * 8 + o] = val;
            }
        }
    }
}

extern "C" void kernel_launch(void* const* d_in, const int* in_sizes, int n_in,
                              void* d_out, int out_size, void* d_ws, size_t ws_size,
                              hipStream_t stream) {
    const float* cart   = (const float*)d_in[0];
    const int*   aidx   = (const int*)d_in[1];
    const int*   spec   = (const int*)d_in[2];
    const float* ccoeff = (const float*)d_in[4];
    const float* embn_W1 = (const float*)d_in[5];
    const float* embn_b1 = (const float*)d_in[6];
    const float* embn_g  = (const float*)d_in[7];
    const float* embn_be = (const float*)d_in[8];
    const float* embn_W2 = (const float*)d_in[9];
    const float* embn_b2 = (const float*)d_in[10];
    const float* embc_W1 = (const float*)d_in[11];
    const float* embc_b1 = (const float*)d_in[12];
    const float* embc_g  = (const float*)d_in[13];
    const float* embc_be = (const float*)d_in[14];
    const float* embc_W2 = (const float*)d_in[15];
    const float* embc_b2 = (const float*)d_in[16];
    const float* oc_W1 = (const float*)d_in[17];
    const float* oc_b1 = (const float*)d_in[18];
    const float* oc_g  = (const float*)d_in[19];
    const float* oc_be = (const float*)d_in[20];
    const float* oc_W2 = (const float*)d_in[21];
    const float* oc_b2 = (const float*)d_in[22];
    const float* out_W1 = (const float*)d_in[23];
    const float* out_b1 = (const float*)d_in[24];
    const float* out_g  = (const float*)d_in[25];
    const float* out_be = (const float*)d_in[26];
    const float* out_W2 = (const float*)d_in[27];
    const float* out_b2 = (const float*)d_in[28];

    float* outp = (float*)d_out;

    char* ws = (char*)d_ws;
    size_t off = 0;
    auto carve = [&](size_t bytes) { size_t o = off; off = (off + bytes + 255) & ~(size_t)255; return o; };
    ushort_t* ang16 = (ushort_t*)(ws + carve((size_t)4 * NPADC * 2));
    ushort_t* rad16 = (ushort_t*)(ws + carve((size_t)8 * NPADC * 2));
    int*   keyv    = (int*)(ws + carve((size_t)NPADC * 4));
    int*   neigh   = (int*)(ws + carve((size_t)NPADC * 4));
    int*   plist   = (int*)(ws + carve((size_t)NPADC * 4));
    float* ccenter = (float*)(ws + carve((size_t)NATOMS * 64 * 4));
    float* co0     = (float*)(ws + carve((size_t)NATOMS * 32 * 4));
    float* Sa      = (float*)(ws + carve((size_t)NATOMS * 8 * 4));
    float* Sb      = (float*)(ws + carve((size_t)NATOMS * 8 * 4));
    float* table   = (float*)(ws + carve((size_t)TBLN * 24 * 4));
    int*   cnt     = (int*)(ws + carve((size_t)NATOMS * 4));
    int*   offs    = (int*)(ws + carve((size_t)(NATOMS + 1) * 4));
    int*   cursor  = (int*)(ws + carve((size_t)NATOMS * 4));

    hipMemsetAsync(cnt, 0, (size_t)NATOMS * 4, stream);
    k_hist<<<NPAIRS / 256, 256, 0, stream>>>(aidx, cart, cnt, plist, outp);
    k_scan<<<1, 1024, 0, stream>>>(cnt, offs, cursor);
    k_scatter<<<NPAIRS / 256, 256, 0, stream>>>(aidx, cursor, plist);

    k_emb<<<CBLK + TBLK, 256, 0, stream>>>(spec,
                                           embc_W1, embc_b1, embc_g, embc_be, embc_W2, embc_b2,
                                           ccenter,
                                           embn_W1, embn_b1, embn_g, embn_be, embn_W2, embn_b2,
                                           table);

    k_pair2<<<NPADC / 256, 256, 0, stream>>>(cart, aidx, spec, table, plist, offs + NATOMS,
                                             ang16, rad16, keyv, neigh);

    // pass 0: co0 + oc0 -> Sa
    k_pass<true, false><<<NATOMS / APB, 256, 0, stream>>>(
        offs, ang16, rad16, keyv, table, neigh, nullptr, co0, ccenter,
        ccoeff + 0 * 1024, oc_W1 + 0 * 4096, oc_b1 + 0 * 64, oc_g + 0 * 64,
        oc_be + 0 * 64, oc_W2 + 0 * 512, oc_b2 + 0 * 8, spec, Sa);
    // pass 1: S=Sa -> Sb (= Sa + oc1)
    k_pass<false, false><<<NATOMS / APB, 256, 0, stream>>>(
        offs, ang16, rad16, keyv, table, neigh, Sa, co0, ccenter,
        ccoeff + 1 * 1024, oc_W1 + 1 * 4096, oc_b1 + 1 * 64, oc_g + 1 * 64,
        oc_be + 1 * 64, oc_W2 + 1 * 512, oc_b2 + 1 * 8, spec, Sb);
    // pass 2: S=Sb -> Sa (= Sb + oc2)
    k_pass<false, false><<<NATOMS / APB, 256, 0, stream>>>(
        offs, ang16, rad16, keyv, table, neigh, Sb, co0, ccenter,
        ccoeff + 2 * 1024, oc_W1 + 2 * 4096, oc_b1 + 2 * 64, oc_g + 2 * 64,
        oc_be + 2 * 64, oc_W2 + 2 * 512, oc_b2 + 2 * 8, spec, Sa);
    // final: S=Sa -> output
    k_pass<false, true><<<NATOMS / APB, 256, 0, stream>>>(
        offs, ang16, rad16, keyv, table, neigh, Sa, co0, ccenter,
        ccoeff + 3 * 1024, out_W1, out_b1, out_g, out_be,
        out_W2, out_b2, spec, outp + (size_t)NPAIRS * 3);
}